// Round 13
// baseline (647.170 us; speedup 1.0000x reference)
//
#include <hip/hip_runtime.h>
#include <hip/hip_bf16.h>

#define NN 100000
#define NE 1600000
#define DD 128
#define DFF 256
#define BN_EPS 1e-5f
#define NND ((size_t)NN * DD)
#define NTILE 6250   // NN/16
#define CAP 64       // bucket capacity per node (deg ~ Poisson(16), 12-sigma margin)

typedef __attribute__((ext_vector_type(8))) short short8;
typedef __attribute__((ext_vector_type(4))) float f32x4;
typedef __attribute__((ext_vector_type(4))) unsigned short us4;

static __device__ __forceinline__ unsigned short f2bf(float f) {
  union { float f; unsigned u; } v; v.f = f;
  unsigned r = v.u + 0x7fffu + ((v.u >> 16) & 1u);
  return (unsigned short)(r >> 16);
}
static __device__ __forceinline__ float bf2f(unsigned short h) {
  union { unsigned u; float f; } v; v.u = ((unsigned)h) << 16;
  return v.f;
}

// ---- prep + bucket scatter fused: BW work hides under atomic latency --------
__global__ __launch_bounds__(256) void k_prepscat(const float* __restrict__ x,
    unsigned short* __restrict__ xbf,
    const float* __restrict__ w1g, const float* __restrict__ w2g,
    const float* __restrict__ ffw1, const float* __restrict__ ffw2,
    unsigned short* __restrict__ w1t, unsigned short* __restrict__ w2t,
    unsigned short* __restrict__ fw1t, unsigned short* __restrict__ fw2t,
    const int* __restrict__ ei, int* __restrict__ cnt,
    long long* __restrict__ el2) {
  int b = blockIdx.x;
  if (b < 6250) {
    size_t base = ((size_t)b * 256u + threadIdx.x) * 8;
    const f32x4* xp = reinterpret_cast<const f32x4*>(x + base);
    f32x4 a0 = xp[0], a1 = xp[1];
    short8 o;
#pragma unroll
    for (int j = 0; j < 4; ++j) o[j] = (short)f2bf(a0[j]);
#pragma unroll
    for (int j = 0; j < 4; ++j) o[4 + j] = (short)f2bf(a1[j]);
    *reinterpret_cast<short8*>(xbf + base) = o;
  } else if (b < 6634) {
    int i = (b - 6250) * 256 + threadIdx.x;
    if (i < 16384) { int c = i & 127, k = i >> 7; w1t[c * 128 + k] = f2bf(w1g[k * 128 + c]); }
    else if (i < 32768) { i -= 16384; int c = i & 127, k = i >> 7; w2t[c * 128 + k] = f2bf(w2g[k * 128 + c]); }
    else if (i < 65536) { i -= 32768; int c = i & 255, k = i >> 8; fw1t[c * 128 + k] = f2bf(ffw1[k * 256 + c]); }
    else if (i < 98304) { i -= 65536; int c = i & 127, k = i >> 7; fw2t[c * 256 + k] = f2bf(ffw2[k * 128 + c]); }
  } else {
    int e = (b - 6634) * 256 + threadIdx.x;
    if (e < NE) {
      int s = ei[e], d = ei[NE + e];
      int p = atomicAdd(&cnt[d], 1);
      if (p < CAP) {
        long long pk = (long long)((unsigned long long)(unsigned)e |
                                   ((unsigned long long)(unsigned)s << 32));
        __builtin_nontemporal_store(pk, &el2[d * CAP + p]);  // layout == int2{e,s}
      }
    }
  }
}

// ---- gather: 32 lanes/node, 4-deep pipeline, bucket ranges, nt ea loads -----
__global__ __launch_bounds__(256) void k_gather(
    const unsigned short* __restrict__ xbf, const float* __restrict__ ea,
    const int* __restrict__ cnt, const int2* __restrict__ el2,
    unsigned short* __restrict__ h0) {
  int n = blockIdx.x * 8 + (threadIdx.x >> 5);
  int q = threadIdx.x & 31;
  int deg = cnt[n];
  deg = deg > CAP ? CAP : deg;
  int beg = n * CAP;
  int end = beg + deg;
  f32x4 acc = (f32x4){0.f, 0.f, 0.f, 0.f};
  int2 E0 = make_int2(0, 0), E1 = E0, E2 = E0, E3 = E0;
  int i = beg;
  if (i     < end) E0 = el2[i];
  if (i + 1 < end) E1 = el2[i + 1];
  if (i + 2 < end) E2 = el2[i + 2];
  if (i + 3 < end) E3 = el2[i + 3];
  for (; i + 4 <= end; i += 4) {
    f32x4 ev0 = __builtin_nontemporal_load(reinterpret_cast<const f32x4*>(ea + (size_t)E0.x * DD) + q);
    us4  xv0 = *reinterpret_cast<const us4*>(xbf + (size_t)E0.y * DD + q * 4);
    f32x4 ev1 = __builtin_nontemporal_load(reinterpret_cast<const f32x4*>(ea + (size_t)E1.x * DD) + q);
    us4  xv1 = *reinterpret_cast<const us4*>(xbf + (size_t)E1.y * DD + q * 4);
    f32x4 ev2 = __builtin_nontemporal_load(reinterpret_cast<const f32x4*>(ea + (size_t)E2.x * DD) + q);
    us4  xv2 = *reinterpret_cast<const us4*>(xbf + (size_t)E2.y * DD + q * 4);
    f32x4 ev3 = __builtin_nontemporal_load(reinterpret_cast<const f32x4*>(ea + (size_t)E3.x * DD) + q);
    us4  xv3 = *reinterpret_cast<const us4*>(xbf + (size_t)E3.y * DD + q * 4);
    int2 N0 = E0, N1 = E1, N2 = E2, N3 = E3;
    if (i + 4 < end) N0 = el2[i + 4];
    if (i + 5 < end) N1 = el2[i + 5];
    if (i + 6 < end) N2 = el2[i + 6];
    if (i + 7 < end) N3 = el2[i + 7];
#pragma unroll
    for (int c = 0; c < 4; ++c) {
      float m0 = bf2f((unsigned short)xv0[c]) + ev0[c];
      acc[c] += (m0 > 0.f) ? m0 : 0.f;
      float m1 = bf2f((unsigned short)xv1[c]) + ev1[c];
      acc[c] += (m1 > 0.f) ? m1 : 0.f;
      float m2 = bf2f((unsigned short)xv2[c]) + ev2[c];
      acc[c] += (m2 > 0.f) ? m2 : 0.f;
      float m3 = bf2f((unsigned short)xv3[c]) + ev3[c];
      acc[c] += (m3 > 0.f) ? m3 : 0.f;
    }
    E0 = N0; E1 = N1; E2 = N2; E3 = N3;
  }
  if (i < end) {
    f32x4 ev = __builtin_nontemporal_load(reinterpret_cast<const f32x4*>(ea + (size_t)E0.x * DD) + q);
    us4  xv = *reinterpret_cast<const us4*>(xbf + (size_t)E0.y * DD + q * 4);
#pragma unroll
    for (int c = 0; c < 4; ++c) {
      float m = bf2f((unsigned short)xv[c]) + ev[c];
      acc[c] += (m > 0.f) ? m : 0.f;
    }
  }
  if (i + 1 < end) {
    f32x4 ev = __builtin_nontemporal_load(reinterpret_cast<const f32x4*>(ea + (size_t)E1.x * DD) + q);
    us4  xv = *reinterpret_cast<const us4*>(xbf + (size_t)E1.y * DD + q * 4);
#pragma unroll
    for (int c = 0; c < 4; ++c) {
      float m = bf2f((unsigned short)xv[c]) + ev[c];
      acc[c] += (m > 0.f) ? m : 0.f;
    }
  }
  if (i + 2 < end) {
    f32x4 ev = __builtin_nontemporal_load(reinterpret_cast<const f32x4*>(ea + (size_t)E2.x * DD) + q);
    us4  xv = *reinterpret_cast<const us4*>(xbf + (size_t)E2.y * DD + q * 4);
#pragma unroll
    for (int c = 0; c < 4; ++c) {
      float m = bf2f((unsigned short)xv[c]) + ev[c];
      acc[c] += (m > 0.f) ? m : 0.f;
    }
  }
  us4 xs = *reinterpret_cast<const us4*>(xbf + (size_t)n * DD + q * 4);
  union { unsigned short us[4]; unsigned long long u; } pk;
#pragma unroll
  for (int c = 0; c < 4; ++c) pk.us[c] = f2bf(bf2f((unsigned short)xs[c]) + acc[c]);
  *reinterpret_cast<unsigned long long*>(h0 + (size_t)n * DD + q * 4) = pk.u;
}

// ------- MLP1 fused: out = x + relu(relu(h0@W1+b1)@W2+b2), + BN1 stats -------
#define TR1 136
__global__ __launch_bounds__(256) void k_mlp1(const unsigned short* __restrict__ A,
    const unsigned short* __restrict__ W1T, const float* __restrict__ b1,
    const unsigned short* __restrict__ W2T, const float* __restrict__ b2,
    const unsigned short* __restrict__ xbf, float* __restrict__ O,
    float* __restrict__ stats) {
  __shared__ unsigned short tr[4][16 * TR1];
  __shared__ float lds_s[128], lds_q[128];
  if (threadIdx.x < 128) { lds_s[threadIdx.x] = 0.f; lds_q[threadIdx.x] = 0.f; }
  int lane = threadIdx.x & 63, w = threadIdx.x >> 6;
  int tile = blockIdx.x * 4 + w;
  int l15 = lane & 15, g = lane >> 4;
  int row0 = tile * 16;
  __syncthreads();
  if (tile < NTILE) {
    f32x4 acc[8];
#pragma unroll
    for (int ct = 0; ct < 8; ++ct) {
      float b = b1[ct * 16 + l15];
      acc[ct] = (f32x4){b, b, b, b};
    }
    short8 a[4];
#pragma unroll
    for (int kt = 0; kt < 4; ++kt)
      a[kt] = *reinterpret_cast<const short8*>(A + (size_t)(row0 + l15) * DD + kt * 32 + g * 8);
#pragma unroll
    for (int kt = 0; kt < 4; ++kt) {
      int k0 = kt * 32 + g * 8;
#pragma unroll
      for (int ct = 0; ct < 8; ++ct) {
        int c = ct * 16 + l15;
        short8 b = *reinterpret_cast<const short8*>(W1T + (size_t)c * DD + k0);
        acc[ct] = __builtin_amdgcn_mfma_f32_16x16x32_bf16(a[kt], b, acc[ct], 0, 0, 0);
      }
    }
#pragma unroll
    for (int ct = 0; ct < 8; ++ct)
#pragma unroll
      for (int r = 0; r < 4; ++r) {
        float v = acc[ct][r];
        v = v > 0.f ? v : 0.f;
        tr[w][(g * 4 + r) * TR1 + ct * 16 + l15] = f2bf(v);
      }
    // same-wave LDS read-back: no barrier needed (tr is wave-private)
    short8 a2[4];
#pragma unroll
    for (int kt = 0; kt < 4; ++kt)
      a2[kt] = *reinterpret_cast<const short8*>(&tr[w][l15 * TR1 + kt * 32 + g * 8]);
    f32x4 acc2[8];
#pragma unroll
    for (int ct = 0; ct < 8; ++ct) {
      float b = b2[ct * 16 + l15];
      acc2[ct] = (f32x4){b, b, b, b};
    }
#pragma unroll
    for (int kt = 0; kt < 4; ++kt) {
      int k0 = kt * 32 + g * 8;
#pragma unroll
      for (int ct = 0; ct < 8; ++ct) {
        int c = ct * 16 + l15;
        short8 b = *reinterpret_cast<const short8*>(W2T + (size_t)c * DD + k0);
        acc2[ct] = __builtin_amdgcn_mfma_f32_16x16x32_bf16(a2[kt], b, acc2[ct], 0, 0, 0);
      }
    }
#pragma unroll
    for (int ct = 0; ct < 8; ++ct) {
      int c = ct * 16 + l15;
      float s = 0.f, q = 0.f;
#pragma unroll
      for (int r = 0; r < 4; ++r) {
        int row = row0 + g * 4 + r;
        float v = acc2[ct][r];
        v = v > 0.f ? v : 0.f;
        v += bf2f(xbf[(size_t)row * DD + c]);
        O[(size_t)row * DD + c] = v;
        s += v; q += v * v;
      }
      s += __shfl_xor(s, 16); s += __shfl_xor(s, 32);
      q += __shfl_xor(q, 16); q += __shfl_xor(q, 32);
      if (g == 0) { atomicAdd(&lds_s[c], s); atomicAdd(&lds_q[c], q); }
    }
  }
  __syncthreads();
  if (threadIdx.x < 128) {
    atomicAdd(&stats[threadIdx.x], lds_s[threadIdx.x]);
    atomicAdd(&stats[128 + threadIdx.x], lds_q[threadIdx.x]);
  }
}

// --- MLP2 fused (+ per-block BN1 finalize): out = bn1 + FFN(bn1), BN2 stats --
//     residual served from wave-private LDS copy of bn1(out) (saves 51MB read)
#define TR2 264
__global__ __launch_bounds__(256) void k_mlp2(const float* __restrict__ H,
    const float* __restrict__ stats, const float* __restrict__ bn1g,
    const float* __restrict__ bn1b, const unsigned short* __restrict__ FW1T,
    const float* __restrict__ fb1, const unsigned short* __restrict__ FW2T,
    const float* __restrict__ fb2, float* __restrict__ O, float* __restrict__ stats2) {
  __shared__ unsigned short tr[4][16 * TR2];     // 33.8 KB
  __shared__ unsigned short resid[4][16 * DD];   // 16 KB (bn1(out) bf16, wave-private)
  __shared__ float lds_s[128], lds_q[128], ldspar[256];
  int t = threadIdx.x;
  if (t < 128) {
    lds_s[t] = 0.f; lds_q[t] = 0.f;
    float mean = stats[t] * (1.f / NN);
    float var = stats[128 + t] * (1.f / NN) - mean * mean;
    float sc = bn1g[t] * rsqrtf(var + BN_EPS);
    ldspar[t] = sc;
    ldspar[128 + t] = bn1b[t] - mean * sc;
  }
  int lane = t & 63, w = t >> 6;
  int tile = blockIdx.x * 4 + w;
  int l15 = lane & 15, g = lane >> 4;
  int row0 = tile * 16;
  __syncthreads();
  if (tile < NTILE) {
    const float* arow = H + (size_t)(row0 + l15) * DD;
    short8 a1[4];
#pragma unroll
    for (int kt = 0; kt < 4; ++kt) {
      int k0 = kt * 32 + g * 8;
      f32x4 u0 = *reinterpret_cast<const f32x4*>(arow + k0);
      f32x4 u1 = *reinterpret_cast<const f32x4*>(arow + k0 + 4);
      short8 af;
#pragma unroll
      for (int j = 0; j < 4; ++j)
        af[j] = (short)f2bf(ldspar[k0 + j] * u0[j] + ldspar[128 + k0 + j]);
#pragma unroll
      for (int j = 0; j < 4; ++j)
        af[4 + j] = (short)f2bf(ldspar[k0 + 4 + j] * u1[j] + ldspar[128 + k0 + 4 + j]);
      a1[kt] = af;
      *reinterpret_cast<short8*>(&resid[w][l15 * DD + k0]) = af;  // stash bn1 row
    }
    f32x4 acc1[16];
#pragma unroll
    for (int ct = 0; ct < 16; ++ct) {
      float b = fb1[ct * 16 + l15];
      acc1[ct] = (f32x4){b, b, b, b};
    }
#pragma unroll
    for (int kt = 0; kt < 4; ++kt) {
      int k0 = kt * 32 + g * 8;
#pragma unroll
      for (int ct = 0; ct < 16; ++ct) {
        int c = ct * 16 + l15;
        short8 b = *reinterpret_cast<const short8*>(FW1T + (size_t)c * DD + k0);
        acc1[ct] = __builtin_amdgcn_mfma_f32_16x16x32_bf16(a1[kt], b, acc1[ct], 0, 0, 0);
      }
    }
#pragma unroll
    for (int ct = 0; ct < 16; ++ct)
#pragma unroll
      for (int r = 0; r < 4; ++r) {
        float v = acc1[ct][r];
        v = v > 0.f ? v : 0.f;
        tr[w][(g * 4 + r) * TR2 + ct * 16 + l15] = f2bf(v);
      }
    // same-wave LDS read-back: no barrier needed
    short8 a2[8];
#pragma unroll
    for (int kt = 0; kt < 8; ++kt)
      a2[kt] = *reinterpret_cast<const short8*>(&tr[w][l15 * TR2 + kt * 32 + g * 8]);
    f32x4 acc2[8];
#pragma unroll
    for (int ct = 0; ct < 8; ++ct) {
      float b = fb2[ct * 16 + l15];
      acc2[ct] = (f32x4){b, b, b, b};
    }
#pragma unroll 2
    for (int kt = 0; kt < 8; ++kt) {
      int k0 = kt * 32 + g * 8;
#pragma unroll
      for (int ct = 0; ct < 8; ++ct) {
        int c = ct * 16 + l15;
        short8 b = *reinterpret_cast<const short8*>(FW2T + (size_t)c * DFF + k0);
        acc2[ct] = __builtin_amdgcn_mfma_f32_16x16x32_bf16(a2[kt], b, acc2[ct], 0, 0, 0);
      }
    }
#pragma unroll
    for (int ct = 0; ct < 8; ++ct) {
      int c = ct * 16 + l15;
      float s = 0.f, q = 0.f;
#pragma unroll
      for (int r = 0; r < 4; ++r) {
        int row = row0 + g * 4 + r;
        float h1v = bf2f(resid[w][(g * 4 + r) * DD + c]);   // bn1(out) from LDS
        float v = acc2[ct][r] + h1v;
        O[(size_t)row * DD + c] = v;
        s += v; q += v * v;
      }
      s += __shfl_xor(s, 16); s += __shfl_xor(s, 32);
      q += __shfl_xor(q, 16); q += __shfl_xor(q, 32);
      if (g == 0) { atomicAdd(&lds_s[c], s); atomicAdd(&lds_q[c], q); }
    }
  }
  __syncthreads();
  if (t < 128) {
    atomicAdd(&stats2[t], lds_s[t]);
    atomicAdd(&stats2[128 + t], lds_q[t]);
  }
}

// ------- final: out = bn2(out) in place (BN2 finalize fused) -----------------
__global__ __launch_bounds__(256) void k_bnfinal(float* __restrict__ h,
    const float* __restrict__ st, const float* __restrict__ gm,
    const float* __restrict__ bt) {
  size_t base = ((size_t)blockIdx.x * 256u + threadIdx.x) * 4;
  int c0 = (int)(base & 127);
  f32x4 v = *reinterpret_cast<f32x4*>(h + base);
#pragma unroll
  for (int j = 0; j < 4; ++j) {
    int c = c0 + j;
    float mean = st[c] * (1.f / NN);
    float var = st[128 + c] * (1.f / NN) - mean * mean;
    float sc = gm[c] * rsqrtf(var + BN_EPS);
    float sh = bt[c] - mean * sc;
    v[j] = sc * v[j] + sh;
  }
  *reinterpret_cast<f32x4*>(h + base) = v;
}

extern "C" void kernel_launch(void* const* d_in, const int* in_sizes, int n_in,
                              void* d_out, int out_size, void* d_ws, size_t ws_size,
                              hipStream_t stream) {
  const float* x    = (const float*)d_in[0];
  const float* ea   = (const float*)d_in[1];
  const float* w1g  = (const float*)d_in[2];
  const float* b1g  = (const float*)d_in[3];
  const float* w2g  = (const float*)d_in[4];
  const float* b2g  = (const float*)d_in[5];
  const float* bn1g = (const float*)d_in[6];
  const float* bn1b = (const float*)d_in[7];
  const float* ffw1 = (const float*)d_in[8];
  const float* ffb1 = (const float*)d_in[9];
  const float* ffw2 = (const float*)d_in[10];
  const float* ffb2 = (const float*)d_in[11];
  const float* bn2g = (const float*)d_in[12];
  const float* bn2b = (const float*)d_in[13];
  const int*   eidx = (const int*)d_in[14];
  float* out = (float*)d_out;

  char* ws = (char*)d_ws;
  long long* el2ll = (long long*)(ws);                 // 51.2 MB (NN*CAP*8)
  int2* el2    = (int2*)(ws);                          // same buffer, int2 view
  int*  cnt    = (int*)(ws + 51200000);                // 400 KB
  float* stats = (float*)(ws + 51600000);              // 2 KB (BN1+BN2)
  unsigned short* w1t  = (unsigned short*)(ws + 51602048);
  unsigned short* w2t  = (unsigned short*)(ws + 51634816);
  unsigned short* fw1t = (unsigned short*)(ws + 51667584);
  unsigned short* fw2t = (unsigned short*)(ws + 51733120);
  unsigned short* xbf  = (unsigned short*)(ws + 51798656);  // 25.6 MB
  unsigned short* hbf  = (unsigned short*)(ws + 77398656);  // 25.6 MB

  // one memset covers cnt (400000 B) + stats (2048 B), contiguous
  hipMemsetAsync(cnt, 0, 402048, stream);

  // prep (xbf + weights) + bucket scatter, one launch (BW ∥ atomic latency)
  k_prepscat<<<12884, 256, 0, stream>>>(x, xbf, w1g, w2g, ffw1, ffw2,
                                        w1t, w2t, fw1t, fw2t, eidx, cnt, el2ll);

  k_gather<<<12500, 256, 0, stream>>>(xbf, ea, cnt, el2, hbf);

  k_mlp1<<<1563, 256, 0, stream>>>(hbf, w1t, b1g, w2t, b2g, xbf, out, stats);
  k_mlp2<<<1563, 256, 0, stream>>>(out, stats, bn1g, bn1b,
                                   fw1t, ffb1, fw2t, ffb2, out, stats + 256);
  k_bnfinal<<<12500, 256, 0, stream>>>(out, stats + 256, bn2g, bn2b);
}

// Round 14
// 625.258 us; speedup vs baseline: 1.0350x; 1.0350x over previous
//
#include <hip/hip_runtime.h>
#include <hip/hip_bf16.h>

#define NN 100000
#define NE 1600000
#define DD 128
#define DFF 256
#define BN_EPS 1e-5f
#define NND ((size_t)NN * DD)
#define NTILE 6250   // NN/16
#define CAP 64       // bucket capacity per node (deg ~ Poisson(16), 12-sigma margin)

typedef __attribute__((ext_vector_type(8))) short short8;
typedef __attribute__((ext_vector_type(4))) float f32x4;
typedef __attribute__((ext_vector_type(4))) unsigned short us4;

static __device__ __forceinline__ unsigned short f2bf(float f) {
  union { float f; unsigned u; } v; v.f = f;
  unsigned r = v.u + 0x7fffu + ((v.u >> 16) & 1u);
  return (unsigned short)(r >> 16);
}
static __device__ __forceinline__ float bf2f(unsigned short h) {
  union { unsigned u; float f; } v; v.u = ((unsigned)h) << 16;
  return v.f;
}

// ---- prep: xbf = bf16(x) + 4 transposed bf16 weight copies ------------------
__global__ __launch_bounds__(256) void k_prep(const float* __restrict__ x,
    unsigned short* __restrict__ xbf,
    const float* __restrict__ w1g, const float* __restrict__ w2g,
    const float* __restrict__ ffw1, const float* __restrict__ ffw2,
    unsigned short* __restrict__ w1t, unsigned short* __restrict__ w2t,
    unsigned short* __restrict__ fw1t, unsigned short* __restrict__ fw2t) {
  int b = blockIdx.x;
  if (b < 6250) {
    size_t base = ((size_t)b * 256u + threadIdx.x) * 8;
    const f32x4* xp = reinterpret_cast<const f32x4*>(x + base);
    f32x4 a0 = xp[0], a1 = xp[1];
    short8 o;
#pragma unroll
    for (int j = 0; j < 4; ++j) o[j] = (short)f2bf(a0[j]);
#pragma unroll
    for (int j = 0; j < 4; ++j) o[4 + j] = (short)f2bf(a1[j]);
    *reinterpret_cast<short8*>(xbf + base) = o;
  } else {
    int i = (b - 6250) * 256 + threadIdx.x;
    if (i < 16384) { int c = i & 127, k = i >> 7; w1t[c * 128 + k] = f2bf(w1g[k * 128 + c]); }
    else if (i < 32768) { i -= 16384; int c = i & 127, k = i >> 7; w2t[c * 128 + k] = f2bf(w2g[k * 128 + c]); }
    else if (i < 65536) { i -= 32768; int c = i & 255, k = i >> 8; fw1t[c * 128 + k] = f2bf(ffw1[k * 256 + c]); }
    else if (i < 98304) { i -= 65536; int c = i & 127, k = i >> 7; fw2t[c * 256 + k] = f2bf(ffw2[k * 128 + c]); }
  }
}

// ---- bucket scatter: el2[d*CAP + p] = (edge, src), p = cnt[d]++ -------------
__global__ __launch_bounds__(256) void k_scatter(const int* __restrict__ ei,
                                                 int* __restrict__ cnt,
                                                 int2* __restrict__ el2) {
  int e = blockIdx.x * 256 + threadIdx.x;
  if (e >= NE) return;
  int s = ei[e], d = ei[NE + e];
  int p = atomicAdd(&cnt[d], 1);
  if (p < CAP) el2[d * CAP + p] = make_int2(e, s);
}

// ---- gather v2: indices staged in LDS (kills el2 dependent-load chain),
//      2-chunk register double-buffer (8 ea-rows in flight per group) --------
#define GLOAD(ev, xv, base)                                                    \
  do {                                                                         \
    _Pragma("unroll")                                                          \
    for (int j = 0; j < 4; ++j) {                                              \
      int2 E = sidx[g][(base) + j];                                            \
      ev[j] = *(reinterpret_cast<const f32x4*>(ea + (size_t)E.x * DD) + q);    \
      xv[j] = *reinterpret_cast<const us4*>(xbf + (size_t)E.y * DD + q * 4);   \
    }                                                                          \
  } while (0)

#define GCONS(ev, xv, cval)                                                    \
  do {                                                                         \
    _Pragma("unroll")                                                          \
    for (int j = 0; j < 4; ++j) {                                              \
      if (j < (cval)) {                                                        \
        _Pragma("unroll")                                                      \
        for (int c = 0; c < 4; ++c) {                                          \
          float m = bf2f((unsigned short)xv[j][c]) + ev[j][c];                 \
          acc[c] += (m > 0.f) ? m : 0.f;                                       \
        }                                                                      \
      }                                                                        \
    }                                                                          \
  } while (0)

__global__ __launch_bounds__(256) void k_gather(
    const unsigned short* __restrict__ xbf, const float* __restrict__ ea,
    const int* __restrict__ cnt, const int2* __restrict__ el2,
    unsigned short* __restrict__ h0) {
  __shared__ int2 sidx[8][CAP];
  int g = threadIdx.x >> 5;
  int n = blockIdx.x * 8 + g;
  int q = threadIdx.x & 31;
  int deg = cnt[n];
  deg = deg > CAP ? CAP : deg;
  int pad4 = (deg + 3) & ~3;
  int beg = n * CAP;
  // coalesced bucket index fetch: 512B contiguous per group, 2 slots/lane
  if (q < deg) sidx[g][q] = el2[beg + q];
  else if (q < pad4) sidx[g][q] = make_int2(0, 0);
  int q2 = q + 32;
  if (q2 < deg) sidx[g][q2] = el2[beg + q2];
  else if (q2 < pad4) sidx[g][q2] = make_int2(0, 0);
  // same-wave LDS RAW: DS ops are program-ordered within a wave, no barrier

  f32x4 acc = (f32x4){0.f, 0.f, 0.f, 0.f};
  int nch = (deg + 3) >> 2;
  f32x4 evA[4], evB[4];
  us4 xvA[4], xvB[4];
  if (nch > 0) {
    GLOAD(evA, xvA, 0);
    if (nch > 1) GLOAD(evB, xvB, 4);
    for (int c = 0; c < nch; c += 2) {
      int cA = deg - c * 4; cA = cA > 4 ? 4 : cA;
      GCONS(evA, xvA, cA);
      if (c + 2 < nch) GLOAD(evA, xvA, (c + 2) * 4);
      if (c + 1 < nch) {
        int cB = deg - (c + 1) * 4; cB = cB > 4 ? 4 : cB;
        GCONS(evB, xvB, cB);
        if (c + 3 < nch) GLOAD(evB, xvB, (c + 3) * 4);
      }
    }
  }
  us4 xs = *reinterpret_cast<const us4*>(xbf + (size_t)n * DD + q * 4);
  union { unsigned short us[4]; unsigned long long u; } pk;
#pragma unroll
  for (int c = 0; c < 4; ++c) pk.us[c] = f2bf(bf2f((unsigned short)xs[c]) + acc[c]);
  *reinterpret_cast<unsigned long long*>(h0 + (size_t)n * DD + q * 4) = pk.u;
}

// ------- MLP1 fused: out = x + relu(relu(h0@W1+b1)@W2+b2), + BN1 stats -------
#define TR1 136
__global__ __launch_bounds__(256) void k_mlp1(const unsigned short* __restrict__ A,
    const unsigned short* __restrict__ W1T, const float* __restrict__ b1,
    const unsigned short* __restrict__ W2T, const float* __restrict__ b2,
    const unsigned short* __restrict__ xbf, float* __restrict__ O,
    float* __restrict__ stats) {
  __shared__ unsigned short tr[4][16 * TR1];
  __shared__ float lds_s[128], lds_q[128];
  if (threadIdx.x < 128) { lds_s[threadIdx.x] = 0.f; lds_q[threadIdx.x] = 0.f; }
  int lane = threadIdx.x & 63, w = threadIdx.x >> 6;
  int tile = blockIdx.x * 4 + w;
  int l15 = lane & 15, g = lane >> 4;
  int row0 = tile * 16;
  __syncthreads();
  if (tile < NTILE) {
    f32x4 acc[8];
#pragma unroll
    for (int ct = 0; ct < 8; ++ct) {
      float b = b1[ct * 16 + l15];
      acc[ct] = (f32x4){b, b, b, b};
    }
    short8 a[4];
#pragma unroll
    for (int kt = 0; kt < 4; ++kt)
      a[kt] = *reinterpret_cast<const short8*>(A + (size_t)(row0 + l15) * DD + kt * 32 + g * 8);
#pragma unroll
    for (int kt = 0; kt < 4; ++kt) {
      int k0 = kt * 32 + g * 8;
#pragma unroll
      for (int ct = 0; ct < 8; ++ct) {
        int c = ct * 16 + l15;
        short8 b = *reinterpret_cast<const short8*>(W1T + (size_t)c * DD + k0);
        acc[ct] = __builtin_amdgcn_mfma_f32_16x16x32_bf16(a[kt], b, acc[ct], 0, 0, 0);
      }
    }
#pragma unroll
    for (int ct = 0; ct < 8; ++ct)
#pragma unroll
      for (int r = 0; r < 4; ++r) {
        float v = acc[ct][r];
        v = v > 0.f ? v : 0.f;
        tr[w][(g * 4 + r) * TR1 + ct * 16 + l15] = f2bf(v);
      }
    // same-wave LDS read-back (tr is wave-private)
    short8 a2[4];
#pragma unroll
    for (int kt = 0; kt < 4; ++kt)
      a2[kt] = *reinterpret_cast<const short8*>(&tr[w][l15 * TR1 + kt * 32 + g * 8]);
    f32x4 acc2[8];
#pragma unroll
    for (int ct = 0; ct < 8; ++ct) {
      float b = b2[ct * 16 + l15];
      acc2[ct] = (f32x4){b, b, b, b};
    }
#pragma unroll
    for (int kt = 0; kt < 4; ++kt) {
      int k0 = kt * 32 + g * 8;
#pragma unroll
      for (int ct = 0; ct < 8; ++ct) {
        int c = ct * 16 + l15;
        short8 b = *reinterpret_cast<const short8*>(W2T + (size_t)c * DD + k0);
        acc2[ct] = __builtin_amdgcn_mfma_f32_16x16x32_bf16(a2[kt], b, acc2[ct], 0, 0, 0);
      }
    }
#pragma unroll
    for (int ct = 0; ct < 8; ++ct) {
      int c = ct * 16 + l15;
      float s = 0.f, q = 0.f;
#pragma unroll
      for (int r = 0; r < 4; ++r) {
        int row = row0 + g * 4 + r;
        float v = acc2[ct][r];
        v = v > 0.f ? v : 0.f;
        v += bf2f(xbf[(size_t)row * DD + c]);
        O[(size_t)row * DD + c] = v;
        s += v; q += v * v;
      }
      s += __shfl_xor(s, 16); s += __shfl_xor(s, 32);
      q += __shfl_xor(q, 16); q += __shfl_xor(q, 32);
      if (g == 0) { atomicAdd(&lds_s[c], s); atomicAdd(&lds_q[c], q); }
    }
  }
  __syncthreads();
  if (threadIdx.x < 128) {
    atomicAdd(&stats[threadIdx.x], lds_s[threadIdx.x]);
    atomicAdd(&stats[128 + threadIdx.x], lds_q[threadIdx.x]);
  }
}

// --- MLP2 fused (+ per-block BN1 finalize): out = bn1 + FFN(bn1), BN2 stats --
#define TR2 264
__global__ __launch_bounds__(256) void k_mlp2(const float* __restrict__ H,
    const float* __restrict__ stats, const float* __restrict__ bn1g,
    const float* __restrict__ bn1b, const unsigned short* __restrict__ FW1T,
    const float* __restrict__ fb1, const unsigned short* __restrict__ FW2T,
    const float* __restrict__ fb2, float* __restrict__ O, float* __restrict__ stats2) {
  __shared__ unsigned short tr[4][16 * TR2];
  __shared__ float lds_s[128], lds_q[128], ldspar[256];
  int t = threadIdx.x;
  if (t < 128) {
    lds_s[t] = 0.f; lds_q[t] = 0.f;
    float mean = stats[t] * (1.f / NN);
    float var = stats[128 + t] * (1.f / NN) - mean * mean;
    float sc = bn1g[t] * rsqrtf(var + BN_EPS);
    ldspar[t] = sc;
    ldspar[128 + t] = bn1b[t] - mean * sc;
  }
  int lane = t & 63, w = t >> 6;
  int tile = blockIdx.x * 4 + w;
  int l15 = lane & 15, g = lane >> 4;
  int row0 = tile * 16;
  __syncthreads();
  if (tile < NTILE) {
    const float* arow = H + (size_t)(row0 + l15) * DD;
    short8 a1[4];
#pragma unroll
    for (int kt = 0; kt < 4; ++kt) {
      int k0 = kt * 32 + g * 8;
      f32x4 u0 = *reinterpret_cast<const f32x4*>(arow + k0);
      f32x4 u1 = *reinterpret_cast<const f32x4*>(arow + k0 + 4);
      short8 af;
#pragma unroll
      for (int j = 0; j < 4; ++j)
        af[j] = (short)f2bf(ldspar[k0 + j] * u0[j] + ldspar[128 + k0 + j]);
#pragma unroll
      for (int j = 0; j < 4; ++j)
        af[4 + j] = (short)f2bf(ldspar[k0 + 4 + j] * u1[j] + ldspar[128 + k0 + 4 + j]);
      a1[kt] = af;
    }
    f32x4 acc1[16];
#pragma unroll
    for (int ct = 0; ct < 16; ++ct) {
      float b = fb1[ct * 16 + l15];
      acc1[ct] = (f32x4){b, b, b, b};
    }
#pragma unroll
    for (int kt = 0; kt < 4; ++kt) {
      int k0 = kt * 32 + g * 8;
#pragma unroll
      for (int ct = 0; ct < 16; ++ct) {
        int c = ct * 16 + l15;
        short8 b = *reinterpret_cast<const short8*>(FW1T + (size_t)c * DD + k0);
        acc1[ct] = __builtin_amdgcn_mfma_f32_16x16x32_bf16(a1[kt], b, acc1[ct], 0, 0, 0);
      }
    }
#pragma unroll
    for (int ct = 0; ct < 16; ++ct)
#pragma unroll
      for (int r = 0; r < 4; ++r) {
        float v = acc1[ct][r];
        v = v > 0.f ? v : 0.f;
        tr[w][(g * 4 + r) * TR2 + ct * 16 + l15] = f2bf(v);
      }
    // same-wave LDS read-back
    short8 a2[8];
#pragma unroll
    for (int kt = 0; kt < 8; ++kt)
      a2[kt] = *reinterpret_cast<const short8*>(&tr[w][l15 * TR2 + kt * 32 + g * 8]);
    f32x4 acc2[8];
#pragma unroll
    for (int ct = 0; ct < 8; ++ct) {
      float b = fb2[ct * 16 + l15];
      acc2[ct] = (f32x4){b, b, b, b};
    }
#pragma unroll 2
    for (int kt = 0; kt < 8; ++kt) {
      int k0 = kt * 32 + g * 8;
#pragma unroll
      for (int ct = 0; ct < 8; ++ct) {
        int c = ct * 16 + l15;
        short8 b = *reinterpret_cast<const short8*>(FW2T + (size_t)c * DFF + k0);
        acc2[ct] = __builtin_amdgcn_mfma_f32_16x16x32_bf16(a2[kt], b, acc2[ct], 0, 0, 0);
      }
    }
#pragma unroll
    for (int ct = 0; ct < 8; ++ct) {
      int c = ct * 16 + l15;
      float sc = ldspar[c], sh = ldspar[128 + c];
      float s = 0.f, q = 0.f;
#pragma unroll
      for (int r = 0; r < 4; ++r) {
        int row = row0 + g * 4 + r;
        float h1v = sc * O[(size_t)row * DD + c] + sh;
        float v = acc2[ct][r] + h1v;
        O[(size_t)row * DD + c] = v;
        s += v; q += v * v;
      }
      s += __shfl_xor(s, 16); s += __shfl_xor(s, 32);
      q += __shfl_xor(q, 16); q += __shfl_xor(q, 32);
      if (g == 0) { atomicAdd(&lds_s[c], s); atomicAdd(&lds_q[c], q); }
    }
  }
  __syncthreads();
  if (t < 128) {
    atomicAdd(&stats2[t], lds_s[t]);
    atomicAdd(&stats2[128 + t], lds_q[t]);
  }
}

// ------- final: out = bn2(out) in place (BN2 finalize fused) -----------------
__global__ __launch_bounds__(256) void k_bnfinal(float* __restrict__ h,
    const float* __restrict__ st, const float* __restrict__ gm,
    const float* __restrict__ bt) {
  size_t base = ((size_t)blockIdx.x * 256u + threadIdx.x) * 4;
  int c0 = (int)(base & 127);
  f32x4 v = *reinterpret_cast<f32x4*>(h + base);
#pragma unroll
  for (int j = 0; j < 4; ++j) {
    int c = c0 + j;
    float mean = st[c] * (1.f / NN);
    float var = st[128 + c] * (1.f / NN) - mean * mean;
    float sc = gm[c] * rsqrtf(var + BN_EPS);
    float sh = bt[c] - mean * sc;
    v[j] = sc * v[j] + sh;
  }
  *reinterpret_cast<f32x4*>(h + base) = v;
}

extern "C" void kernel_launch(void* const* d_in, const int* in_sizes, int n_in,
                              void* d_out, int out_size, void* d_ws, size_t ws_size,
                              hipStream_t stream) {
  const float* x    = (const float*)d_in[0];
  const float* ea   = (const float*)d_in[1];
  const float* w1g  = (const float*)d_in[2];
  const float* b1g  = (const float*)d_in[3];
  const float* w2g  = (const float*)d_in[4];
  const float* b2g  = (const float*)d_in[5];
  const float* bn1g = (const float*)d_in[6];
  const float* bn1b = (const float*)d_in[7];
  const float* ffw1 = (const float*)d_in[8];
  const float* ffb1 = (const float*)d_in[9];
  const float* ffw2 = (const float*)d_in[10];
  const float* ffb2 = (const float*)d_in[11];
  const float* bn2g = (const float*)d_in[12];
  const float* bn2b = (const float*)d_in[13];
  const int*   eidx = (const int*)d_in[14];
  float* out = (float*)d_out;

  char* ws = (char*)d_ws;
  int2* el2    = (int2*)(ws);                          // 51.2 MB (NN*CAP*8)
  int*  cnt    = (int*)(ws + 51200000);                // 400 KB
  float* stats = (float*)(ws + 51600000);              // 2 KB (BN1+BN2)
  unsigned short* w1t  = (unsigned short*)(ws + 51602048);
  unsigned short* w2t  = (unsigned short*)(ws + 51634816);
  unsigned short* fw1t = (unsigned short*)(ws + 51667584);
  unsigned short* fw2t = (unsigned short*)(ws + 51733120);
  unsigned short* xbf  = (unsigned short*)(ws + 51798656);  // 25.6 MB
  unsigned short* hbf  = (unsigned short*)(ws + 77398656);  // 25.6 MB

  // one memset covers cnt (400000 B) + stats (2048 B), contiguous
  hipMemsetAsync(cnt, 0, 402048, stream);

  k_prep<<<6634, 256, 0, stream>>>(x, xbf, w1g, w2g, ffw1, ffw2,
                                   w1t, w2t, fw1t, fw2t);

  k_scatter<<<6250, 256, 0, stream>>>(eidx, cnt, el2);

  k_gather<<<12500, 256, 0, stream>>>(xbf, ea, cnt, el2, hbf);

  k_mlp1<<<1563, 256, 0, stream>>>(hbf, w1t, b1g, w2t, b2g, xbf, out, stats);
  k_mlp2<<<1563, 256, 0, stream>>>(out, stats, bn1g, bn1b,
                                   fw1t, ffb1, fw2t, ffb2, out, stats + 256);
  k_bnfinal<<<12500, 256, 0, stream>>>(out, stats + 256, bn2g, bn2b);
}

// Round 15
// 615.118 us; speedup vs baseline: 1.0521x; 1.0165x over previous
//
#include <hip/hip_runtime.h>
#include <hip/hip_bf16.h>

#define NN 100000
#define NE 1600000
#define DD 128
#define DFF 256
#define BN_EPS 1e-5f
#define NND ((size_t)NN * DD)
#define NTILE 6250   // NN/16
#define CAP 64       // bucket capacity per node (deg ~ Poisson(16), 12-sigma margin)

typedef __attribute__((ext_vector_type(8))) short short8;
typedef __attribute__((ext_vector_type(4))) float f32x4;
typedef __attribute__((ext_vector_type(4))) unsigned short us4;

static __device__ __forceinline__ unsigned short f2bf(float f) {
  union { float f; unsigned u; } v; v.f = f;
  unsigned r = v.u + 0x7fffu + ((v.u >> 16) & 1u);
  return (unsigned short)(r >> 16);
}
static __device__ __forceinline__ float bf2f(unsigned short h) {
  union { unsigned u; float f; } v; v.u = ((unsigned)h) << 16;
  return v.f;
}

// ---- prep: xbf = bf16(x) + 4 transposed bf16 weights + zero cnt/stats -------
__global__ __launch_bounds__(256) void k_prep(const float* __restrict__ x,
    unsigned short* __restrict__ xbf,
    const float* __restrict__ w1g, const float* __restrict__ w2g,
    const float* __restrict__ ffw1, const float* __restrict__ ffw2,
    unsigned short* __restrict__ w1t, unsigned short* __restrict__ w2t,
    unsigned short* __restrict__ fw1t, unsigned short* __restrict__ fw2t,
    int* __restrict__ cnt, float* __restrict__ stats) {
  int b = blockIdx.x;
  if (b < 6250) {
    size_t base = ((size_t)b * 256u + threadIdx.x) * 8;
    const f32x4* xp = reinterpret_cast<const f32x4*>(x + base);
    f32x4 a0 = xp[0], a1 = xp[1];
    short8 o;
#pragma unroll
    for (int j = 0; j < 4; ++j) o[j] = (short)f2bf(a0[j]);
#pragma unroll
    for (int j = 0; j < 4; ++j) o[4 + j] = (short)f2bf(a1[j]);
    *reinterpret_cast<short8*>(xbf + base) = o;
  } else if (b < 6634) {
    int i = (b - 6250) * 256 + threadIdx.x;
    if (i < 16384) { int c = i & 127, k = i >> 7; w1t[c * 128 + k] = f2bf(w1g[k * 128 + c]); }
    else if (i < 32768) { i -= 16384; int c = i & 127, k = i >> 7; w2t[c * 128 + k] = f2bf(w2g[k * 128 + c]); }
    else if (i < 65536) { i -= 32768; int c = i & 255, k = i >> 8; fw1t[c * 128 + k] = f2bf(ffw1[k * 256 + c]); }
    else if (i < 98304) { i -= 65536; int c = i & 127, k = i >> 7; fw2t[c * 256 + k] = f2bf(ffw2[k * 128 + c]); }
  } else {
    int i = (b - 6634) * 256 + threadIdx.x;   // zero cnt[NN] + stats[512]
    if (i < NN) cnt[i] = 0;
    else if (i < NN + 512) stats[i - NN] = 0.f;
  }
}

// ---- bucket scatter: el2[d*CAP + p] = (edge, src), p = cnt[d]++ -------------
__global__ __launch_bounds__(256) void k_scatter(const int* __restrict__ ei,
                                                 int* __restrict__ cnt,
                                                 int2* __restrict__ el2) {
  int e = blockIdx.x * 256 + threadIdx.x;
  if (e >= NE) return;
  int s = ei[e], d = ei[NE + e];
  int p = atomicAdd(&cnt[d], 1);
  if (p < CAP) el2[d * CAP + p] = make_int2(e, s);
}

// ---- gather v3: LDS-staged indices + 3-chunk register pipeline (12 rows) ----
#define GLOAD(ev, xv, base)                                                    \
  do {                                                                         \
    _Pragma("unroll")                                                          \
    for (int j = 0; j < 4; ++j) {                                              \
      int2 E = sidx[g][(base) + j];                                            \
      ev[j] = *(reinterpret_cast<const f32x4*>(ea + (size_t)E.x * DD) + q);    \
      xv[j] = *reinterpret_cast<const us4*>(xbf + (size_t)E.y * DD + q * 4);   \
    }                                                                          \
  } while (0)

#define GCONS(ev, xv, cval)                                                    \
  do {                                                                         \
    _Pragma("unroll")                                                          \
    for (int j = 0; j < 4; ++j) {                                              \
      if (j < (cval)) {                                                        \
        _Pragma("unroll")                                                      \
        for (int c = 0; c < 4; ++c) {                                          \
          float m = bf2f((unsigned short)xv[j][c]) + ev[j][c];                 \
          acc[c] += (m > 0.f) ? m : 0.f;                                       \
        }                                                                      \
      }                                                                        \
    }                                                                          \
  } while (0)

__global__ __launch_bounds__(256) void k_gather(
    const unsigned short* __restrict__ xbf, const float* __restrict__ ea,
    const int* __restrict__ cnt, const int2* __restrict__ el2,
    unsigned short* __restrict__ h0) {
  __shared__ int2 sidx[8][CAP];
  int g = threadIdx.x >> 5;
  int n = blockIdx.x * 8 + g;
  int q = threadIdx.x & 31;
  int deg = cnt[n];
  deg = deg > CAP ? CAP : deg;
  int pad4 = (deg + 3) & ~3;
  int beg = n * CAP;
  // coalesced bucket index fetch: 512B contiguous per group, 2 slots/lane
  if (q < deg) sidx[g][q] = el2[beg + q];
  else if (q < pad4) sidx[g][q] = make_int2(0, 0);
  int q2 = q + 32;
  if (q2 < deg) sidx[g][q2] = el2[beg + q2];
  else if (q2 < pad4) sidx[g][q2] = make_int2(0, 0);
  // same-wave LDS RAW: DS ops are program-ordered within a wave, no barrier

  f32x4 acc = (f32x4){0.f, 0.f, 0.f, 0.f};
  int nch = (deg + 3) >> 2;
  f32x4 evA[4], evB[4], evC[4];
  us4 xvA[4], xvB[4], xvC[4];
  if (nch > 0) {
    GLOAD(evA, xvA, 0);
    if (nch > 1) GLOAD(evB, xvB, 4);
    if (nch > 2) GLOAD(evC, xvC, 8);
    for (int c = 0; c < nch; c += 3) {
      int cA = deg - c * 4; cA = cA > 4 ? 4 : cA;
      GCONS(evA, xvA, cA);
      if (c + 3 < nch) GLOAD(evA, xvA, (c + 3) * 4);
      if (c + 1 < nch) {
        int cB = deg - (c + 1) * 4; cB = cB > 4 ? 4 : cB;
        GCONS(evB, xvB, cB);
        if (c + 4 < nch) GLOAD(evB, xvB, (c + 4) * 4);
        if (c + 2 < nch) {
          int cC = deg - (c + 2) * 4; cC = cC > 4 ? 4 : cC;
          GCONS(evC, xvC, cC);
          if (c + 5 < nch) GLOAD(evC, xvC, (c + 5) * 4);
        }
      }
    }
  }
  us4 xs = *reinterpret_cast<const us4*>(xbf + (size_t)n * DD + q * 4);
  union { unsigned short us[4]; unsigned long long u; } pk;
#pragma unroll
  for (int c = 0; c < 4; ++c) pk.us[c] = f2bf(bf2f((unsigned short)xs[c]) + acc[c]);
  *reinterpret_cast<unsigned long long*>(h0 + (size_t)n * DD + q * 4) = pk.u;
}

// ------- MLP1 fused: out = x + relu(relu(h0@W1+b1)@W2+b2), + BN1 stats -------
#define TR1 136
__global__ __launch_bounds__(256) void k_mlp1(const unsigned short* __restrict__ A,
    const unsigned short* __restrict__ W1T, const float* __restrict__ b1,
    const unsigned short* __restrict__ W2T, const float* __restrict__ b2,
    const unsigned short* __restrict__ xbf, float* __restrict__ O,
    float* __restrict__ stats) {
  __shared__ unsigned short tr[4][16 * TR1];
  __shared__ float lds_s[128], lds_q[128];
  if (threadIdx.x < 128) { lds_s[threadIdx.x] = 0.f; lds_q[threadIdx.x] = 0.f; }
  int lane = threadIdx.x & 63, w = threadIdx.x >> 6;
  int tile = blockIdx.x * 4 + w;
  int l15 = lane & 15, g = lane >> 4;
  int row0 = tile * 16;
  __syncthreads();
  if (tile < NTILE) {
    f32x4 acc[8];
#pragma unroll
    for (int ct = 0; ct < 8; ++ct) {
      float b = b1[ct * 16 + l15];
      acc[ct] = (f32x4){b, b, b, b};
    }
    short8 a[4];
#pragma unroll
    for (int kt = 0; kt < 4; ++kt)
      a[kt] = *reinterpret_cast<const short8*>(A + (size_t)(row0 + l15) * DD + kt * 32 + g * 8);
#pragma unroll
    for (int kt = 0; kt < 4; ++kt) {
      int k0 = kt * 32 + g * 8;
#pragma unroll
      for (int ct = 0; ct < 8; ++ct) {
        int c = ct * 16 + l15;
        short8 b = *reinterpret_cast<const short8*>(W1T + (size_t)c * DD + k0);
        acc[ct] = __builtin_amdgcn_mfma_f32_16x16x32_bf16(a[kt], b, acc[ct], 0, 0, 0);
      }
    }
#pragma unroll
    for (int ct = 0; ct < 8; ++ct)
#pragma unroll
      for (int r = 0; r < 4; ++r) {
        float v = acc[ct][r];
        v = v > 0.f ? v : 0.f;
        tr[w][(g * 4 + r) * TR1 + ct * 16 + l15] = f2bf(v);
      }
    // same-wave LDS read-back (tr is wave-private)
    short8 a2[4];
#pragma unroll
    for (int kt = 0; kt < 4; ++kt)
      a2[kt] = *reinterpret_cast<const short8*>(&tr[w][l15 * TR1 + kt * 32 + g * 8]);
    f32x4 acc2[8];
#pragma unroll
    for (int ct = 0; ct < 8; ++ct) {
      float b = b2[ct * 16 + l15];
      acc2[ct] = (f32x4){b, b, b, b};
    }
#pragma unroll
    for (int kt = 0; kt < 4; ++kt) {
      int k0 = kt * 32 + g * 8;
#pragma unroll
      for (int ct = 0; ct < 8; ++ct) {
        int c = ct * 16 + l15;
        short8 b = *reinterpret_cast<const short8*>(W2T + (size_t)c * DD + k0);
        acc2[ct] = __builtin_amdgcn_mfma_f32_16x16x32_bf16(a2[kt], b, acc2[ct], 0, 0, 0);
      }
    }
#pragma unroll
    for (int ct = 0; ct < 8; ++ct) {
      int c = ct * 16 + l15;
      float s = 0.f, q = 0.f;
#pragma unroll
      for (int r = 0; r < 4; ++r) {
        int row = row0 + g * 4 + r;
        float v = acc2[ct][r];
        v = v > 0.f ? v : 0.f;
        v += bf2f(xbf[(size_t)row * DD + c]);
        O[(size_t)row * DD + c] = v;
        s += v; q += v * v;
      }
      s += __shfl_xor(s, 16); s += __shfl_xor(s, 32);
      q += __shfl_xor(q, 16); q += __shfl_xor(q, 32);
      if (g == 0) { atomicAdd(&lds_s[c], s); atomicAdd(&lds_q[c], q); }
    }
  }
  __syncthreads();
  if (threadIdx.x < 128) {
    atomicAdd(&stats[threadIdx.x], lds_s[threadIdx.x]);
    atomicAdd(&stats[128 + threadIdx.x], lds_q[threadIdx.x]);
  }
}

// --- MLP2 fused (+ per-block BN1 finalize): out = bn1 + FFN(bn1), BN2 stats --
#define TR2 264
__global__ __launch_bounds__(256) void k_mlp2(const float* __restrict__ H,
    const float* __restrict__ stats, const float* __restrict__ bn1g,
    const float* __restrict__ bn1b, const unsigned short* __restrict__ FW1T,
    const float* __restrict__ fb1, const unsigned short* __restrict__ FW2T,
    const float* __restrict__ fb2, float* __restrict__ O, float* __restrict__ stats2) {
  __shared__ unsigned short tr[4][16 * TR2];
  __shared__ float lds_s[128], lds_q[128], ldspar[256];
  int t = threadIdx.x;
  if (t < 128) {
    lds_s[t] = 0.f; lds_q[t] = 0.f;
    float mean = stats[t] * (1.f / NN);
    float var = stats[128 + t] * (1.f / NN) - mean * mean;
    float sc = bn1g[t] * rsqrtf(var + BN_EPS);
    ldspar[t] = sc;
    ldspar[128 + t] = bn1b[t] - mean * sc;
  }
  int lane = t & 63, w = t >> 6;
  int tile = blockIdx.x * 4 + w;
  int l15 = lane & 15, g = lane >> 4;
  int row0 = tile * 16;
  __syncthreads();
  if (tile < NTILE) {
    const float* arow = H + (size_t)(row0 + l15) * DD;
    short8 a1[4];
#pragma unroll
    for (int kt = 0; kt < 4; ++kt) {
      int k0 = kt * 32 + g * 8;
      f32x4 u0 = *reinterpret_cast<const f32x4*>(arow + k0);
      f32x4 u1 = *reinterpret_cast<const f32x4*>(arow + k0 + 4);
      short8 af;
#pragma unroll
      for (int j = 0; j < 4; ++j)
        af[j] = (short)f2bf(ldspar[k0 + j] * u0[j] + ldspar[128 + k0 + j]);
#pragma unroll
      for (int j = 0; j < 4; ++j)
        af[4 + j] = (short)f2bf(ldspar[k0 + 4 + j] * u1[j] + ldspar[128 + k0 + 4 + j]);
      a1[kt] = af;
    }
    f32x4 acc1[16];
#pragma unroll
    for (int ct = 0; ct < 16; ++ct) {
      float b = fb1[ct * 16 + l15];
      acc1[ct] = (f32x4){b, b, b, b};
    }
#pragma unroll
    for (int kt = 0; kt < 4; ++kt) {
      int k0 = kt * 32 + g * 8;
#pragma unroll
      for (int ct = 0; ct < 16; ++ct) {
        int c = ct * 16 + l15;
        short8 b = *reinterpret_cast<const short8*>(FW1T + (size_t)c * DD + k0);
        acc1[ct] = __builtin_amdgcn_mfma_f32_16x16x32_bf16(a1[kt], b, acc1[ct], 0, 0, 0);
      }
    }
#pragma unroll
    for (int ct = 0; ct < 16; ++ct)
#pragma unroll
      for (int r = 0; r < 4; ++r) {
        float v = acc1[ct][r];
        v = v > 0.f ? v : 0.f;
        tr[w][(g * 4 + r) * TR2 + ct * 16 + l15] = f2bf(v);
      }
    // same-wave LDS read-back
    short8 a2[8];
#pragma unroll
    for (int kt = 0; kt < 8; ++kt)
      a2[kt] = *reinterpret_cast<const short8*>(&tr[w][l15 * TR2 + kt * 32 + g * 8]);
    f32x4 acc2[8];
#pragma unroll
    for (int ct = 0; ct < 8; ++ct) {
      float b = fb2[ct * 16 + l15];
      acc2[ct] = (f32x4){b, b, b, b};
    }
#pragma unroll 2
    for (int kt = 0; kt < 8; ++kt) {
      int k0 = kt * 32 + g * 8;
#pragma unroll
      for (int ct = 0; ct < 8; ++ct) {
        int c = ct * 16 + l15;
        short8 b = *reinterpret_cast<const short8*>(FW2T + (size_t)c * DFF + k0);
        acc2[ct] = __builtin_amdgcn_mfma_f32_16x16x32_bf16(a2[kt], b, acc2[ct], 0, 0, 0);
      }
    }
#pragma unroll
    for (int ct = 0; ct < 8; ++ct) {
      int c = ct * 16 + l15;
      float sc = ldspar[c], sh = ldspar[128 + c];
      float s = 0.f, q = 0.f;
#pragma unroll
      for (int r = 0; r < 4; ++r) {
        int row = row0 + g * 4 + r;
        float h1v = sc * O[(size_t)row * DD + c] + sh;
        float v = acc2[ct][r] + h1v;
        O[(size_t)row * DD + c] = v;
        s += v; q += v * v;
      }
      s += __shfl_xor(s, 16); s += __shfl_xor(s, 32);
      q += __shfl_xor(q, 16); q += __shfl_xor(q, 32);
      if (g == 0) { atomicAdd(&lds_s[c], s); atomicAdd(&lds_q[c], q); }
    }
  }
  __syncthreads();
  if (t < 128) {
    atomicAdd(&stats2[t], lds_s[t]);
    atomicAdd(&stats2[128 + t], lds_q[t]);
  }
}

// ------- final: out = bn2(out) in place (BN2 finalize fused) -----------------
__global__ __launch_bounds__(256) void k_bnfinal(float* __restrict__ h,
    const float* __restrict__ st, const float* __restrict__ gm,
    const float* __restrict__ bt) {
  size_t base = ((size_t)blockIdx.x * 256u + threadIdx.x) * 4;
  int c0 = (int)(base & 127);
  f32x4 v = *reinterpret_cast<f32x4*>(h + base);
#pragma unroll
  for (int j = 0; j < 4; ++j) {
    int c = c0 + j;
    float mean = st[c] * (1.f / NN);
    float var = st[128 + c] * (1.f / NN) - mean * mean;
    float sc = gm[c] * rsqrtf(var + BN_EPS);
    float sh = bt[c] - mean * sc;
    v[j] = sc * v[j] + sh;
  }
  *reinterpret_cast<f32x4*>(h + base) = v;
}

extern "C" void kernel_launch(void* const* d_in, const int* in_sizes, int n_in,
                              void* d_out, int out_size, void* d_ws, size_t ws_size,
                              hipStream_t stream) {
  const float* x    = (const float*)d_in[0];
  const float* ea   = (const float*)d_in[1];
  const float* w1g  = (const float*)d_in[2];
  const float* b1g  = (const float*)d_in[3];
  const float* w2g  = (const float*)d_in[4];
  const float* b2g  = (const float*)d_in[5];
  const float* bn1g = (const float*)d_in[6];
  const float* bn1b = (const float*)d_in[7];
  const float* ffw1 = (const float*)d_in[8];
  const float* ffb1 = (const float*)d_in[9];
  const float* ffw2 = (const float*)d_in[10];
  const float* ffb2 = (const float*)d_in[11];
  const float* bn2g = (const float*)d_in[12];
  const float* bn2b = (const float*)d_in[13];
  const int*   eidx = (const int*)d_in[14];
  float* out = (float*)d_out;

  char* ws = (char*)d_ws;
  int2* el2    = (int2*)(ws);                          // 51.2 MB (NN*CAP*8)
  int*  cnt    = (int*)(ws + 51200000);                // 400 KB
  float* stats = (float*)(ws + 51600000);              // 2 KB (BN1+BN2)
  unsigned short* w1t  = (unsigned short*)(ws + 51602048);
  unsigned short* w2t  = (unsigned short*)(ws + 51634816);
  unsigned short* fw1t = (unsigned short*)(ws + 51667584);
  unsigned short* fw2t = (unsigned short*)(ws + 51733120);
  unsigned short* xbf  = (unsigned short*)(ws + 51798656);  // 25.6 MB
  unsigned short* hbf  = (unsigned short*)(ws + 77398656);  // 25.6 MB

  // prep also zeros cnt+stats (blocks 6634..7026) — no memset dispatch
  k_prep<<<7027, 256, 0, stream>>>(x, xbf, w1g, w2g, ffw1, ffw2,
                                   w1t, w2t, fw1t, fw2t, cnt, stats);

  k_scatter<<<6250, 256, 0, stream>>>(eidx, cnt, el2);

  k_gather<<<12500, 256, 0, stream>>>(xbf, ea, cnt, el2, hbf);

  k_mlp1<<<1563, 256, 0, stream>>>(hbf, w1t, b1g, w2t, b2g, xbf, out, stats);
  k_mlp2<<<1563, 256, 0, stream>>>(out, stats, bn1g, bn1b,
                                   fw1t, ffb1, fw2t, ffb2, out, stats + 256);
  k_bnfinal<<<12500, 256, 0, stream>>>(out, stats + 256, bn2g, bn2b);
}